// Round 4
// baseline (234.842 us; speedup 1.0000x reference)
//
#include <hip/hip_runtime.h>

// ISNELayer: out[t] = mean_{e: tgt[e]==t} emb[node_ids[src[e]]]
// R4 = R3 with the nontemporal-store type fixed (native ext_vector float4).

#define NUM_NODES 100000
#define HIDDEN    128
#define NUM_EDGES 625000

typedef float vfloat4 __attribute__((ext_vector_type(4)));   // native vector for NT store

// --- 1. histogram of targets -------------------------------------------------
__global__ __launch_bounds__(256) void hist_kernel(
    const int* __restrict__ tgt, int* __restrict__ cnt)
{
    int e = blockIdx.x * blockDim.x + threadIdx.x;
    if (e < NUM_EDGES) atomicAdd(&cnt[tgt[e]], 1);
}

// --- 2. single-workgroup exclusive scan over cnt[0..N) -----------------------
// 1024 threads, 4 elements/thread/iter -> 4096/iter, 25 iters.
// Writes offsets[0..N] (offsets[N]=E) and cursor[0..N) = offsets[0..N).
__global__ __launch_bounds__(1024) void scan_kernel(
    const int* __restrict__ cnt, int* __restrict__ offsets,
    int* __restrict__ cursor)
{
    __shared__ int wsum[16];
    const int tid  = threadIdx.x;
    const int lane = tid & 63;
    const int wave = tid >> 6;
    int carry = 0;
    const int CHUNK = 4096;

    for (int base = 0; base < NUM_NODES; base += CHUNK) {
        int idx = base + tid * 4;
        int4 v = make_int4(0, 0, 0, 0);
        if (idx < NUM_NODES)   // N % 4 == 0, so an int4 never straddles the end
            v = *reinterpret_cast<const int4*>(cnt + idx);
        int tsum = v.x + v.y + v.z + v.w;

        // inclusive wave scan of tsum
        int incl = tsum;
        #pragma unroll
        for (int d = 1; d < 64; d <<= 1) {
            int t = __shfl_up(incl, d, 64);
            if (lane >= d) incl += t;
        }
        if (lane == 63) wsum[wave] = incl;
        __syncthreads();

        if (wave == 0) {
            int ws = (lane < 16) ? wsum[lane] : 0;
            #pragma unroll
            for (int d = 1; d < 16; d <<= 1) {
                int t = __shfl_up(ws, d, 64);
                if (lane >= d) ws += t;
            }
            if (lane < 16) wsum[lane] = ws;   // inclusive over waves
        }
        __syncthreads();

        int wave_prefix = (wave > 0) ? wsum[wave - 1] : 0;
        int excl = carry + wave_prefix + (incl - tsum);
        int4 o;
        o.x = excl;
        o.y = o.x + v.x;
        o.z = o.y + v.y;
        o.w = o.z + v.z;
        if (idx < NUM_NODES) {
            *reinterpret_cast<int4*>(offsets + idx) = o;
            *reinterpret_cast<int4*>(cursor  + idx) = o;
        }
        carry += wsum[15];     // chunk total
        __syncthreads();       // protect wsum against next-iter overwrite
    }
    if (tid == 0) offsets[NUM_NODES] = NUM_EDGES;
}

// --- 3. permute: bucket source node ids by target ----------------------------
__global__ __launch_bounds__(256) void permute_kernel(
    const int* __restrict__ node_ids, const int* __restrict__ src,
    const int* __restrict__ tgt, int* __restrict__ cursor,
    int* __restrict__ sorted_src)
{
    int e = blockIdx.x * blockDim.x + threadIdx.x;
    if (e < NUM_EDGES) {
        int pos = atomicAdd(&cursor[tgt[e]], 1);
        sorted_src[pos] = node_ids[src[e]];
    }
}

// --- 4. gather-mean: 32 lanes per output row, register accumulation ----------
__global__ __launch_bounds__(256) void gather_kernel(
    const int* __restrict__ offsets, const int* __restrict__ sorted_src,
    const float* __restrict__ emb, float* __restrict__ out)
{
    int gid  = blockIdx.x * blockDim.x + threadIdx.x;
    int n    = gid >> 5;
    int lane = gid & 31;
    if (n >= NUM_NODES) return;

    int beg = offsets[n], end = offsets[n + 1];
    float4 acc0 = make_float4(0.f, 0.f, 0.f, 0.f);
    float4 acc1 = make_float4(0.f, 0.f, 0.f, 0.f);
    int i = beg;
    for (; i + 3 < end; i += 4) {            // 4 row loads in flight
        int s0 = sorted_src[i + 0];
        int s1 = sorted_src[i + 1];
        int s2 = sorted_src[i + 2];
        int s3 = sorted_src[i + 3];
        const float4 a = *reinterpret_cast<const float4*>(emb + (size_t)s0 * HIDDEN + lane * 4);
        const float4 b = *reinterpret_cast<const float4*>(emb + (size_t)s1 * HIDDEN + lane * 4);
        const float4 c = *reinterpret_cast<const float4*>(emb + (size_t)s2 * HIDDEN + lane * 4);
        const float4 d = *reinterpret_cast<const float4*>(emb + (size_t)s3 * HIDDEN + lane * 4);
        acc0.x += a.x + b.x; acc0.y += a.y + b.y; acc0.z += a.z + b.z; acc0.w += a.w + b.w;
        acc1.x += c.x + d.x; acc1.y += c.y + d.y; acc1.z += c.z + d.z; acc1.w += c.w + d.w;
    }
    for (; i < end; ++i) {
        int s0 = sorted_src[i];
        const float4 a = *reinterpret_cast<const float4*>(emb + (size_t)s0 * HIDDEN + lane * 4);
        acc0.x += a.x; acc0.y += a.y; acc0.z += a.z; acc0.w += a.w;
    }
    float inv = (end > beg) ? 1.0f / (float)(end - beg) : 0.0f;
    vfloat4 r;
    r.x = (acc0.x + acc1.x) * inv;
    r.y = (acc0.y + acc1.y) * inv;
    r.z = (acc0.z + acc1.z) * inv;
    r.w = (acc0.w + acc1.w) * inv;
    __builtin_nontemporal_store(r,
        reinterpret_cast<vfloat4*>(out + (size_t)n * HIDDEN + lane * 4));
}

extern "C" void kernel_launch(void* const* d_in, const int* in_sizes, int n_in,
                              void* d_out, int out_size, void* d_ws, size_t ws_size,
                              hipStream_t stream) {
    const int*   node_ids = (const int*)d_in[0];
    const int*   edge_idx = (const int*)d_in[1];   // [2, E]: row0 src, row1 tgt
    const float* emb      = (const float*)d_in[2];
    float*       out      = (float*)d_out;

    const int* edge_src = edge_idx;
    const int* edge_tgt = edge_idx + NUM_EDGES;

    // workspace layout (16B-aligned chunks)
    char* ws = (char*)d_ws;
    int* cnt        = (int*)(ws + 0);         // 400000 B
    int* offsets    = (int*)(ws + 400000);    // 400016 B (N+1 ints, padded)
    int* cursor     = (int*)(ws + 800016);    // 400000 B
    int* sorted_src = (int*)(ws + 1200016);   // 2500000 B  -> total ~3.7 MB

    (void)hipMemsetAsync(cnt, 0, NUM_NODES * sizeof(int), stream);

    int eb = (NUM_EDGES + 255) / 256;
    hist_kernel<<<eb, 256, 0, stream>>>(edge_tgt, cnt);
    scan_kernel<<<1, 1024, 0, stream>>>(cnt, offsets, cursor);
    permute_kernel<<<eb, 256, 0, stream>>>(node_ids, edge_src, edge_tgt,
                                           cursor, sorted_src);
    {
        long long total = (long long)NUM_NODES * 32;
        int grid = (int)((total + 255) / 256);
        gather_kernel<<<grid, 256, 0, stream>>>(offsets, sorted_src, emb, out);
    }
}